// Round 1
// baseline (8789.614 us; speedup 1.0000x reference)
//
#include <hip/hip_runtime.h>
#include <math.h>

#define H 128
#define LDSTR 68   // LDS row stride in floats: rows 16B-aligned (68*4=272=17*16), banks spread

__device__ __forceinline__ float silu_f(float v) {
    // x * sigmoid(x) = x / (1 + exp(-x)); saturates correctly for |v| large
    return v / (1.0f + __expf(-v));
}

// Inner-product tile: acc[j][i] += sum_k buf[k][eb+i] * W[k*H + fb+j]
// buf is [128][LDSTR] LDS (K-major, edge-minor). W row-major [128][H].
__device__ __forceinline__ void gemm128(const float (*__restrict__ buf)[LDSTR],
                                        const float* __restrict__ W,
                                        int fb, int eb, float acc[8][4]) {
#pragma unroll 4
    for (int k = 0; k < H; ++k) {
        const float4 a4  = *(const float4*)&buf[k][eb];
        const float4 w04 = *(const float4*)&W[k * H + fb];
        const float4 w14 = *(const float4*)&W[k * H + fb + 4];
        const float av[4] = {a4.x, a4.y, a4.z, a4.w};
        const float wv[8] = {w04.x, w04.y, w04.z, w04.w, w14.x, w14.y, w14.z, w14.w};
#pragma unroll
        for (int j = 0; j < 8; ++j)
#pragma unroll
            for (int i = 0; i < 4; ++i)
                acc[j][i] = fmaf(wv[j], av[i], acc[j][i]);
    }
}

// ---------------- input embedding + first linear ----------------
__global__ void __launch_bounds__(256)
input_kernel(const float* __restrict__ node_scalar, const int* __restrict__ type_ids,
             const float* __restrict__ emb, const float* __restrict__ W_in,
             const float* __restrict__ b_in, float* __restrict__ hout,
             int NN, int ntypes)
{
    const int idx = blockIdx.x * 256 + threadIdx.x;
    if (idx >= NN * H) return;
    const int n = idx >> 7;       // /H
    const int f = idx & (H - 1);
    int t = type_ids[n];
    t = t < 0 ? 0 : (t >= ntypes ? ntypes - 1 : t);
    float s = b_in[f];
#pragma unroll
    for (int k = 0; k < 5; ++k) s = fmaf(node_scalar[n * 5 + k], W_in[k * H + f], s);
#pragma unroll
    for (int k = 0; k < 8; ++k) s = fmaf(emb[t * 8 + k], W_in[(5 + k) * H + f], s);
    hout[idx] = s;
}

// ---------------- per-layer edge kernel (fused edge MLP + coord MLP + scatters) ----
__global__ void __launch_bounds__(256, 2)
edge_kernel(const float* __restrict__ x, const float* __restrict__ h,
            const int* __restrict__ src, const int* __restrict__ dst,
            const float* __restrict__ eW1, const float* __restrict__ eb1,
            const float* __restrict__ eW2, const float* __restrict__ eb2,
            const float* __restrict__ eW3, const float* __restrict__ eb3,
            const float* __restrict__ cW1, const float* __restrict__ cb1,
            const float* __restrict__ cW2, const float* __restrict__ cb2,
            float* __restrict__ m_aggr, float* __restrict__ dxv,
            int E)
{
    __shared__ float bufA[H][LDSTR];
    __shared__ float bufB[H][LDSTR];
    __shared__ float d2s[64];
    __shared__ float relx[64], rely[64], relz[64];
    __shared__ int   ssrc[64], sdst[64];
    __shared__ int   evalid[64];

    const int tid = threadIdx.x;
    const int e0  = blockIdx.x * 64;

    // phase 0: per-edge geometry
    if (tid < 64) {
        int e = e0 + tid;
        int v = (e < E) ? 1 : 0;
        if (!v) e = E - 1;
        evalid[tid] = v;
        const int s = src[e], d = dst[e];
        ssrc[tid] = s; sdst[tid] = d;
        const float rx = x[3 * s + 0] - x[3 * d + 0];
        const float ry = x[3 * s + 1] - x[3 * d + 1];
        const float rz = x[3 * s + 2] - x[3 * d + 2];
        relx[tid] = rx; rely[tid] = ry; relz[tid] = rz;
        d2s[tid] = rx * rx + ry * ry + rz * rz;
    }
    __syncthreads();

    // gather h[src], h[dst] transposed into LDS: buf[k][e]
    {
        const int fp2 = (tid & 7) * 2;
        const int er  = tid >> 3;     // 0..31
#pragma unroll
        for (int rep = 0; rep < 16; ++rep) {
            const int f = (rep & 7) * 16 + fp2;
            const int e = (rep >> 3) * 32 + er;
            const float2 a = *(const float2*)&h[(size_t)ssrc[e] * H + f];
            const float2 b = *(const float2*)&h[(size_t)sdst[e] * H + f];
            bufA[f][e] = a.x; bufA[f + 1][e] = a.y;
            bufB[f][e] = b.x; bufB[f + 1][e] = b.y;
        }
    }
    __syncthreads();

    const int fg = tid & 15, eg = tid >> 4;
    const int fb = fg * 8, eb = eg * 4;

    float acc[8][4];
    // gemm1: e_in @ eW1 + b1, e_in = [h_src | h_dst | d2]
    {
#pragma unroll
        for (int j = 0; j < 8; ++j) {
            const float bv   = eb1[fb + j];
            const float w256 = eW1[256 * H + fb + j];
#pragma unroll
            for (int i = 0; i < 4; ++i)
                acc[j][i] = fmaf(d2s[eb + i], w256, bv);
        }
    }
    gemm128((const float(*)[LDSTR])bufA, eW1, fb, eb, acc);
    gemm128((const float(*)[LDSTR])bufB, eW1 + H * H, fb, eb, acc);
    __syncthreads();
#pragma unroll
    for (int j = 0; j < 8; ++j)
#pragma unroll
        for (int i = 0; i < 4; ++i)
            bufA[fb + j][eb + i] = silu_f(acc[j][i]);   // m1
    __syncthreads();

    // gemm2
#pragma unroll
    for (int j = 0; j < 8; ++j) {
        const float bv = eb2[fb + j];
#pragma unroll
        for (int i = 0; i < 4; ++i) acc[j][i] = bv;
    }
    gemm128((const float(*)[LDSTR])bufA, eW2, fb, eb, acc);
    __syncthreads();
#pragma unroll
    for (int j = 0; j < 8; ++j)
#pragma unroll
        for (int i = 0; i < 4; ++i)
            bufB[fb + j][eb + i] = silu_f(acc[j][i]);   // m2
    __syncthreads();

    // gemm3 -> m (no activation)
#pragma unroll
    for (int j = 0; j < 8; ++j) {
        const float bv = eb3[fb + j];
#pragma unroll
        for (int i = 0; i < 4; ++i) acc[j][i] = bv;
    }
    gemm128((const float(*)[LDSTR])bufB, eW3, fb, eb, acc);

    // scatter m into m_aggr[src]
#pragma unroll
    for (int i = 0; i < 4; ++i) {
        const int e = eb + i;
        if (evalid[e]) {
            float* dp = &m_aggr[(size_t)ssrc[e] * H + fb];
#pragma unroll
            for (int j = 0; j < 8; ++j) atomicAdd(dp + j, acc[j][i]);
        }
    }
    // stash m for coord MLP (bufA free since gemm2's reads are sync'd)
#pragma unroll
    for (int j = 0; j < 8; ++j)
#pragma unroll
        for (int i = 0; i < 4; ++i)
            bufA[fb + j][eb + i] = acc[j][i];
    __syncthreads();

    // coord MLP: c1 = silu(m @ cW1 + cb1); coef = tanh(c1 @ cW2 + cb2)
#pragma unroll
    for (int j = 0; j < 8; ++j) {
        const float bv = cb1[fb + j];
#pragma unroll
        for (int i = 0; i < 4; ++i) acc[j][i] = bv;
    }
    gemm128((const float(*)[LDSTR])bufA, cW1, fb, eb, acc);

    float c2[8];
#pragma unroll
    for (int j = 0; j < 8; ++j) c2[j] = cW2[fb + j];

    float part[4];
#pragma unroll
    for (int i = 0; i < 4; ++i) {
        float s = 0.f;
#pragma unroll
        for (int j = 0; j < 8; ++j) s = fmaf(silu_f(acc[j][i]), c2[j], s);
        part[i] = s;
    }
    // reduce across the 16 fg lanes (consecutive lanes within wave)
#pragma unroll
    for (int i = 0; i < 4; ++i) {
#pragma unroll
        for (int msk = 1; msk < 16; msk <<= 1)
            part[i] += __shfl_xor(part[i], msk);
    }
    if (fg == 0) {
        const float cb2v = cb2[0];
#pragma unroll
        for (int i = 0; i < 4; ++i) {
            const int e = eb + i;
            if (evalid[e]) {
                const float coef = tanhf(part[i] + cb2v);
                float* dp = &dxv[(size_t)ssrc[e] * 3];
                atomicAdd(dp + 0, relx[e] * coef);
                atomicAdd(dp + 1, rely[e] * coef);
                atomicAdd(dp + 2, relz[e] * coef);
            }
        }
    }
}

// ---------------- per-layer node kernel (x update + node MLP, residual) ----------
__global__ void __launch_bounds__(256, 2)
node_kernel(float* __restrict__ x, const float* __restrict__ dxv,
            float* __restrict__ h, const float* __restrict__ m_aggr,
            const float* __restrict__ nW1, const float* __restrict__ nb1,
            const float* __restrict__ nW2, const float* __restrict__ nb2,
            const float* __restrict__ nW3, const float* __restrict__ nb3,
            int NN)
{
    __shared__ float bufA[H][LDSTR];
    __shared__ float bufB[H][LDSTR];
    const int tid = threadIdx.x;
    const int n0  = blockIdx.x * 64;

    // x += delta_x for this block's nodes
    if (tid < 192) {
        const int n = n0 + tid / 3;
        if (n < NN) {
            const int c = tid % 3;
            x[(size_t)n * 3 + c] += dxv[(size_t)n * 3 + c];
        }
    }

    // stage h and m_aggr transposed
    {
        const int fp2 = (tid & 7) * 2;
        const int er  = tid >> 3;
#pragma unroll
        for (int rep = 0; rep < 16; ++rep) {
            const int f = (rep & 7) * 16 + fp2;
            const int e = (rep >> 3) * 32 + er;
            int n = n0 + e; if (n >= NN) n = NN - 1;
            const float2 a = *(const float2*)&h[(size_t)n * H + f];
            const float2 b = *(const float2*)&m_aggr[(size_t)n * H + f];
            bufA[f][e] = a.x; bufA[f + 1][e] = a.y;
            bufB[f][e] = b.x; bufB[f + 1][e] = b.y;
        }
    }
    __syncthreads();

    const int fg = tid & 15, eg = tid >> 4;
    const int fb = fg * 8, eb = eg * 4;
    float acc[8][4];

    // gemm1: [h | m_aggr] @ nW1 + b1
#pragma unroll
    for (int j = 0; j < 8; ++j) {
        const float bv = nb1[fb + j];
#pragma unroll
        for (int i = 0; i < 4; ++i) acc[j][i] = bv;
    }
    gemm128((const float(*)[LDSTR])bufA, nW1, fb, eb, acc);
    gemm128((const float(*)[LDSTR])bufB, nW1 + H * H, fb, eb, acc);
    __syncthreads();
#pragma unroll
    for (int j = 0; j < 8; ++j)
#pragma unroll
        for (int i = 0; i < 4; ++i)
            bufA[fb + j][eb + i] = silu_f(acc[j][i]);
    __syncthreads();

    // gemm2
#pragma unroll
    for (int j = 0; j < 8; ++j) {
        const float bv = nb2[fb + j];
#pragma unroll
        for (int i = 0; i < 4; ++i) acc[j][i] = bv;
    }
    gemm128((const float(*)[LDSTR])bufA, nW2, fb, eb, acc);
    __syncthreads();
#pragma unroll
    for (int j = 0; j < 8; ++j)
#pragma unroll
        for (int i = 0; i < 4; ++i)
            bufB[fb + j][eb + i] = silu_f(acc[j][i]);
    __syncthreads();

    // gemm3, residual into h
#pragma unroll
    for (int j = 0; j < 8; ++j) {
        const float bv = nb3[fb + j];
#pragma unroll
        for (int i = 0; i < 4; ++i) acc[j][i] = bv;
    }
    gemm128((const float(*)[LDSTR])bufB, nW3, fb, eb, acc);
#pragma unroll
    for (int i = 0; i < 4; ++i) {
        const int n = n0 + eb + i;
        if (n < NN) {
            float* hp = &h[(size_t)n * H + fb];
#pragma unroll
            for (int j = 0; j < 8; ++j) hp[j] += acc[j][i];
        }
    }
}

// ---------------- readout: z_nodes = h@W_ro + b_ro; z_global = mean ----------
__global__ void __launch_bounds__(256, 2)
readout_kernel(const float* __restrict__ h, const float* __restrict__ W_ro,
               const float* __restrict__ b_ro, float* __restrict__ out, int NN)
{
    __shared__ float bufA[H][LDSTR];
    const int tid = threadIdx.x;
    const int n0  = blockIdx.x * 64;
    {
        const int fp2 = (tid & 7) * 2;
        const int er  = tid >> 3;
#pragma unroll
        for (int rep = 0; rep < 16; ++rep) {
            const int f = (rep & 7) * 16 + fp2;
            const int e = (rep >> 3) * 32 + er;
            int n = n0 + e; if (n >= NN) n = NN - 1;
            const float2 a = *(const float2*)&h[(size_t)n * H + f];
            bufA[f][e] = a.x; bufA[f + 1][e] = a.y;
        }
    }
    __syncthreads();

    const int fg = tid & 15, eg = tid >> 4;
    const int fb = fg * 8, eb = eg * 4;
    float acc[8][4];
#pragma unroll
    for (int j = 0; j < 8; ++j) {
        const float bv = b_ro[fb + j];
#pragma unroll
        for (int i = 0; i < 4; ++i) acc[j][i] = bv;
    }
    gemm128((const float(*)[LDSTR])bufA, W_ro, fb, eb, acc);

    float* zn = out + H;
    const float inv = 1.0f / (float)NN;
#pragma unroll
    for (int j = 0; j < 8; ++j) {
        float s = 0.f;
#pragma unroll
        for (int i = 0; i < 4; ++i) {
            const int n = n0 + eb + i;
            if (n < NN) {
                zn[(size_t)n * H + fb + j] = acc[j][i];
                s += acc[j][i];
            }
        }
        atomicAdd(&out[fb + j], s * inv);
    }
}

extern "C" void kernel_launch(void* const* d_in, const int* in_sizes, int n_in,
                              void* d_out, int out_size, void* d_ws, size_t ws_size,
                              hipStream_t stream) {
    const float* node_pos    = (const float*)d_in[0];
    const float* node_scalar = (const float*)d_in[1];
    const int*   type_ids    = (const int*)d_in[2];
    const int*   edge_index  = (const int*)d_in[3];
    const float* emb         = (const float*)d_in[4];
    const float* W_in        = (const float*)d_in[5];
    const float* b_in        = (const float*)d_in[6];
    const float* eW1 = (const float*)d_in[7];
    const float* eb1 = (const float*)d_in[8];
    const float* eW2 = (const float*)d_in[9];
    const float* eb2 = (const float*)d_in[10];
    const float* eW3 = (const float*)d_in[11];
    const float* eb3 = (const float*)d_in[12];
    const float* cW1 = (const float*)d_in[13];
    const float* cb1 = (const float*)d_in[14];
    const float* cW2 = (const float*)d_in[15];
    const float* cb2 = (const float*)d_in[16];
    const float* nW1 = (const float*)d_in[17];
    const float* nb1 = (const float*)d_in[18];
    const float* nW2 = (const float*)d_in[19];
    const float* nb2 = (const float*)d_in[20];
    const float* nW3 = (const float*)d_in[21];
    const float* nb3 = (const float*)d_in[22];
    const float* W_ro = (const float*)d_in[23];
    const float* b_ro = (const float*)d_in[24];

    const int NN = in_sizes[0] / 3;
    const int E  = in_sizes[3] / 2;
    const int Lc = in_sizes[7] / ((2 * H + 1) * H);
    const int ntypes = in_sizes[4] / 8;

    const int* srcp = edge_index;
    const int* dstp = edge_index + E;

    // h lives in the z_nodes region of d_out (overwritten by readout in-place, per-tile)
    float* hbuf = (float*)d_out + H;

    float* ws     = (float*)d_ws;
    float* m_aggr = ws;                                  // NN*H
    float* xb     = ws + (size_t)NN * H;                 // NN*3
    float* dxb    = xb + (size_t)NN * 3;                 // NN*3

    hipMemcpyAsync(xb, node_pos, sizeof(float) * 3 * (size_t)NN,
                   hipMemcpyDeviceToDevice, stream);
    input_kernel<<<dim3((NN * H + 255) / 256), dim3(256), 0, stream>>>(
        node_scalar, type_ids, emb, W_in, b_in, hbuf, NN, ntypes);

    for (int l = 0; l < Lc; ++l) {
        hipMemsetAsync(m_aggr, 0, sizeof(float) * (size_t)NN * H, stream);
        hipMemsetAsync(dxb, 0, sizeof(float) * (size_t)NN * 3, stream);
        edge_kernel<<<dim3((E + 63) / 64), dim3(256), 0, stream>>>(
            xb, hbuf, srcp, dstp,
            eW1 + (size_t)l * (2 * H + 1) * H, eb1 + (size_t)l * H,
            eW2 + (size_t)l * H * H,           eb2 + (size_t)l * H,
            eW3 + (size_t)l * H * H,           eb3 + (size_t)l * H,
            cW1 + (size_t)l * H * H,           cb1 + (size_t)l * H,
            cW2 + (size_t)l * H,               cb2 + l,
            m_aggr, dxb, E);
        node_kernel<<<dim3((NN + 63) / 64), dim3(256), 0, stream>>>(
            xb, dxb, hbuf, m_aggr,
            nW1 + (size_t)l * 2 * H * H, nb1 + (size_t)l * H,
            nW2 + (size_t)l * H * H,     nb2 + (size_t)l * H,
            nW3 + (size_t)l * H * H,     nb3 + (size_t)l * H, NN);
    }

    hipMemsetAsync(d_out, 0, sizeof(float) * H, stream);
    readout_kernel<<<dim3((NN + 63) / 64), dim3(256), 0, stream>>>(
        hbuf, W_ro, b_ro, (float*)d_out, NN);
}